// Round 1
// baseline (2323.346 us; speedup 1.0000x reference)
//
#include <hip/hip_runtime.h>

typedef __bf16 bf16x8 __attribute__((ext_vector_type(8)));
typedef float f32x4 __attribute__((ext_vector_type(4)));

#define MAXV 448.0f

__device__ __forceinline__ void gld_lds16(const void* g, void* l) {
  __builtin_amdgcn_global_load_lds(
      (const __attribute__((address_space(1))) void*)g,
      (__attribute__((address_space(3))) void*)l, 16, 0, 0);
}

__global__ void init_ws_kernel(unsigned int* p) {
  if (threadIdx.x < 2) p[threadIdx.x] = 0u;
}

__global__ void amax_kernel(const float* __restrict__ in, long n4, unsigned int* out) {
  long i0 = (long)blockIdx.x * blockDim.x + threadIdx.x;
  long stride = (long)gridDim.x * blockDim.x;
  const float4* in4 = (const float4*)in;
  float m = 0.0f;
  for (long i = i0; i < n4; i += stride) {
    float4 v = in4[i];
    m = fmaxf(m, fmaxf(fmaxf(fabsf(v.x), fabsf(v.y)), fmaxf(fabsf(v.z), fabsf(v.w))));
  }
  m = fminf(m, MAXV);  // amax of clipped == min(amax, 448)
#pragma unroll
  for (int off = 32; off >= 1; off >>= 1)
    m = fmaxf(m, __shfl_xor(m, off, 64));
  if ((threadIdx.x & 63) == 0) atomicMax(out, __float_as_uint(m));
}

// Fake-quantize one value into the SCALED domain, return bf16 bits (exact:
// result has a 4-bit significand).
__device__ __forceinline__ unsigned short fq1(float v, float scale) {
  float c = fminf(fmaxf(v, -MAXV), MAXV);
  float s = c * scale;
  float mag = fmaxf(fabsf(s), 1e-12f);          // always a normal fp32
  unsigned int u = __float_as_uint(mag);
  unsigned int E = u >> 23;                     // biased exponent
  // t = 1.mant * 2^3  in [8,16): mag/step with step = 2^floor(log2 mag)/8
  float t = __uint_as_float((u & 0x007fffffu) | (130u << 23));
  float r = rintf(t);                           // round half-to-even (jnp.round)
  float q = r * __uint_as_float((E - 3u) << 23);  // r * 2^(e-3), exact
  float res = (s == 0.0f) ? 0.0f : copysignf(q, s);
  return (unsigned short)(__float_as_uint(res) >> 16);  // exact bf16 truncation
}

__global__ void quant_kernel(const float* __restrict__ in, unsigned short* __restrict__ out,
                             long n4, const unsigned int* __restrict__ amax_p) {
  float amax = fmaxf(__uint_as_float(*amax_p), 1e-12f);
  float scale = MAXV / amax;
  long i0 = (long)blockIdx.x * blockDim.x + threadIdx.x;
  long stride = (long)gridDim.x * blockDim.x;
  const float4* in4 = (const float4*)in;
  ushort4* out4 = (ushort4*)out;
  for (long i = i0; i < n4; i += stride) {
    float4 v = in4[i];
    ushort4 o;
    o.x = fq1(v.x, scale);
    o.y = fq1(v.y, scale);
    o.z = fq1(v.z, scale);
    o.w = fq1(v.w, scale);
    out4[i] = o;
  }
}

// C[m,n] = (sum_k A[m,k]*B[n,k]) * inv_scale + bias[n]
// A: M x K bf16 (row-major), B: N x K bf16 (row-major) == W
#define TM 128
#define TN 128
#define BK 32

__global__ __launch_bounds__(256, 2) void gemm_bt_kernel(
    const unsigned short* __restrict__ A, const unsigned short* __restrict__ B,
    const float* __restrict__ bias, const unsigned int* __restrict__ amax_ws,
    float* __restrict__ C, int M, int N, int K) {
  __shared__ __align__(16) unsigned short As[TM * BK];  // 8 KB, row-major stride 32
  __shared__ __align__(16) unsigned short Bs[TN * BK];  // 8 KB

  const int tid = threadIdx.x;
  const int lane = tid & 63;
  const int wave = tid >> 6;
  const int wm = wave >> 1, wn = wave & 1;  // 2x2 waves of 64x64
  const int bn = blockIdx.x, bm = blockIdx.y;

  const int mfrag = lane & 15;  // m (A) / n (B) within 16x16 tile
  const int kq = lane >> 4;     // k-quad: holds k = kq*8 .. kq*8+7

  // staging: chunk c = p*256+tid covers row c>>2, k-bytes (c&3)*16; LDS byte
  // offset = c*16 -> wave-uniform base + lane*16 as global_load_lds requires.
  const int sr = tid >> 2;
  const int sc = (tid & 3) * 8;
  const unsigned short* gA0 = A + (long)(bm * TM + sr) * K + sc;
  const unsigned short* gA1 = A + (long)(bm * TM + 64 + sr) * K + sc;
  const unsigned short* gB0 = B + (long)(bn * TN + sr) * K + sc;
  const unsigned short* gB1 = B + (long)(bn * TN + 64 + sr) * K + sc;
  unsigned short* lA0 = As + tid * 8;
  unsigned short* lA1 = As + (256 + tid) * 8;
  unsigned short* lB0 = Bs + tid * 8;
  unsigned short* lB1 = Bs + (256 + tid) * 8;

  f32x4 acc[4][4] = {};

  for (int k0 = 0; k0 < K; k0 += BK) {
    __syncthreads();  // prior iter's ds_reads done before overwrite
    gld_lds16(gA0 + k0, lA0);
    gld_lds16(gA1 + k0, lA1);
    gld_lds16(gB0 + k0, lB0);
    gld_lds16(gB1 + k0, lB1);
    __syncthreads();  // compiler drains vmcnt(0) before s_barrier

    bf16x8 af[4], bf[4];
#pragma unroll
    for (int i = 0; i < 4; ++i) {
      af[i] = *(const bf16x8*)(As + (wm * 64 + i * 16 + mfrag) * BK + kq * 8);
      bf[i] = *(const bf16x8*)(Bs + (wn * 64 + i * 16 + mfrag) * BK + kq * 8);
    }
#pragma unroll
    for (int i = 0; i < 4; ++i)
#pragma unroll
      for (int j = 0; j < 4; ++j)
        acc[i][j] = __builtin_amdgcn_mfma_f32_16x16x32_bf16(af[i], bf[j], acc[i][j], 0, 0, 0);
  }

  // epilogue: rescale + bias. C/D layout: col=lane&15, row=(lane>>4)*4+reg
  float amx = fmaxf(__uint_as_float(amax_ws[0]), 1e-12f);
  float amw = fmaxf(__uint_as_float(amax_ws[1]), 1e-12f);
  float sx = MAXV / amx, sw = MAXV / amw;
  float inv = 1.0f / (sx * sw);

  const int row_base = bm * TM + wm * 64 + (lane >> 4) * 4;
  const int col_base = bn * TN + wn * 64 + (lane & 15);
#pragma unroll
  for (int i = 0; i < 4; ++i)
#pragma unroll
    for (int j = 0; j < 4; ++j) {
      int col = col_base + j * 16;
      float bv = bias[col];
#pragma unroll
      for (int r = 0; r < 4; ++r) {
        int row = row_base + i * 16 + r;
        C[(long)row * N + col] = acc[i][j][r] * inv + bv;
      }
    }
}

extern "C" void kernel_launch(void* const* d_in, const int* in_sizes, int n_in,
                              void* d_out, int out_size, void* d_ws, size_t ws_size,
                              hipStream_t stream) {
  const float* x = (const float*)d_in[0];
  const float* w = (const float*)d_in[1];
  const float* bias = (const float*)d_in[2];
  float* out = (float*)d_out;

  const long NX = in_sizes[0];       // B*S*IN_F = 33554432
  const long NW = in_sizes[1];       // OUT_F*IN_F = 67108864
  const int N = in_sizes[2];         // OUT_F = 16384
  const int K = (int)(NW / N);       // 4096
  const int M = (int)(NX / K);       // 8192

  unsigned int* amax = (unsigned int*)d_ws;
  unsigned short* xq = (unsigned short*)((char*)d_ws + 256);
  unsigned short* wq = (unsigned short*)((char*)d_ws + 256 + NX * 2);

  init_ws_kernel<<<1, 64, 0, stream>>>(amax);
  amax_kernel<<<1024, 256, 0, stream>>>(x, NX >> 2, amax + 0);
  amax_kernel<<<2048, 256, 0, stream>>>(w, NW >> 2, amax + 1);
  quant_kernel<<<2048, 256, 0, stream>>>(x, xq, NX >> 2, amax + 0);
  quant_kernel<<<2048, 256, 0, stream>>>(w, wq, NW >> 2, amax + 1);

  dim3 grid(N / TN, M / TM);  // (128, 64)
  gemm_bt_kernel<<<grid, 256, 0, stream>>>(xq, wq, bias, amax, out, M, N, K);
}